// Round 21
// baseline (50.214 us; speedup 1.0000x reference)
//
#include <hip/hip_runtime.h>
#include <hip/hip_fp16.h>

// DifferentiableRankIntegration, B=1024, tau=0.1, K=60.
// R21 = R20 with 7-bit buckets: NB=126, W>=0.5 (band 3.4 -> 1.6 u-units,
// x0.48 on the dominant in-band quartic walk) + 4-term tails (R17-proven;
// r<=e^-W=0.58 at tail start -> err ~0.02 out-units, 2x under threshold).
// Also: nQ>256 handled (two-step phase 4/5 -- fixes latent R18-R20 drop),
// BktQ bucket-parallel fill, bank-skew dropped, 2-chunk wave scans with
// analytic kp^n carries. Pool 26.1KB -> 6 blocks/CU.
// Algorithm: value-bucket compaction, en = e^{u-c_bkt} (cat in mantissa
// LSBs); in-band (ib-1..ib+1): exact weighted quartic rational (1 rcp / 4
// a-terms, numerators via synthetic division, fp16-packed); out-of-band:
// 4-term sigma tails via geometric prefix/suffix tables.

constexpr int B = 1024;
constexpr int NT = 256;
constexpr int NB = 126;
constexpr int SLOTCAP = 1312;      // 1024 + pads (mean 189, 7sigma ~280)
constexpr int QCAP = SLOTCAP / 4;  // 328
constexpr float L2E = 1.4426950408889634f;
constexpr int TCOLS = NB + 6;      // 132

constexpr int OFF_EN  = 0;                        // 5248 B
constexpr int OFF_CQ  = OFF_EN + SLOTCAP * 4;     // Ce+Ch = 2*328*16 = 10496 B
                                                  //  (phase>=5: RankA/P 10496 B)
constexpr int OFF_SEG = OFF_CQ + 2 * QCAP * 16;   // segCnt 2016 + segPre 4032
                                                  //  (phase>=3: Tab 18*132*4 = 9504)
constexpr int OFF_BKQ = OFF_SEG + 18 * TCOLS * 4; // BktQ 328 B
constexpr int OFF_SST = OFF_BKQ + QCAP;           // segStart 127*4 = 508 B
constexpr int OFF_RED = OFF_SST + (NB + 1) * 4;   // Red 32 B
constexpr int POOL_BYTES = ((OFF_RED + 32 + 15) / 16) * 16;  // 26128 -> 52 granules

__global__ __launch_bounds__(NT, 6)
void rank_one_kernel(const float* __restrict__ s_v, const float* __restrict__ s_l,
                     const int* __restrict__ pos_m, const int* __restrict__ neg_m,
                     float* __restrict__ rank_ws) {
    __shared__ __align__(16) char pool[POOL_BYTES];
    float* En          = (float*)(pool + OFF_EN);
    float4* CeAll      = (float4*)(pool + OFF_CQ);
    uint4* ChAll       = (uint4*)(pool + OFF_CQ + QCAP * 16);
    unsigned char (*segCnt)[16]  = (unsigned char(*)[16])(pool + OFF_SEG);
    unsigned short (*segPre)[16] = (unsigned short(*)[16])(pool + OFF_SEG + NB * 16);
    float* TabF        = (float*)(pool + OFF_SEG);   // overlay (post 2b)
    unsigned char* BktQ = (unsigned char*)(pool + OFF_BKQ);
    int* segStart      = (int*)(pool + OFF_SST);
    float* Red         = (float*)(pool + OFF_RED);
    float* RankA       = (float*)(pool + OFF_CQ);    // phase>=5 overlay
    float* RankP       = RankA + SLOTCAP;

    const int m = blockIdx.x >> 10;
    const int r = blockIdx.x & 1023;
    const float* __restrict__ S = m ? s_l : s_v;
    const int tid = threadIdx.x;
    const int lane = tid & 63;
    const int wvid = tid >> 6;
    const unsigned long long lmask = (1ull << lane) - 1ull;

    for (int s = tid; s < SLOTCAP; s += NT) En[s] = 0.f;  // pads: cat bits 0
    for (int j = tid; j < NB * 16 / 4; j += NT) ((int*)segCnt)[j] = 0;
    __syncthreads();

    // ---- Phase 1: read, u = s/tau, cat, row min/max ----
    float uu[4]; int cat[4];
    float mn = 1e30f, mx = -1e30f;
#pragma unroll
    for (int i = 0; i < 4; ++i) {
        const int c = tid + i * NT;
        uu[i] = S[r * B + c] * 10.0f;
        const int pf = pos_m[r * B + c] != 0, nf = neg_m[r * B + c] != 0;
        cat[i] = pf | (nf << 1);
        mn = fminf(mn, uu[i]); mx = fmaxf(mx, uu[i]);
    }
#pragma unroll
    for (int off = 1; off < 64; off <<= 1) {
        mn = fminf(mn, __shfl_xor(mn, off));
        mx = fmaxf(mx, __shfl_xor(mx, off));
    }
    if (lane == 0) { Red[wvid] = mn; Red[4 + wvid] = mx; }
    __syncthreads();

    const float lo = fminf(fminf(Red[0], Red[1]), fminf(Red[2], Red[3]));
    const float hi = fmaxf(fmaxf(Red[4], Red[5]), fmaxf(Red[6], Red[7]));
    const float umin = lo;
    const float Wb   = fmaxf((hi - lo) * (1.0001f / NB), 0.5f);
    const float invW = 1.0f / Wb;
    const float kap1 = exp2f(-Wb * L2E);
    const float kap2 = kap1 * kap1;
    const float eWm  = exp2f(Wb * L2E);

    // ---- Phase 1b: bucket keys; rank via 7 bit-ballots (NB<127, cat0 -> 127) ----
    int key[4], rk[4];
#pragma unroll
    for (int i = 0; i < 4; ++i) {
        int b = (int)((uu[i] - umin) * invW);
        b = b > NB - 1 ? NB - 1 : b;
        const int kk = cat[i] ? b : 127;
        key[i] = b;
        unsigned long long same = ~0ull;
#pragma unroll
        for (int j = 0; j < 7; ++j) {
            const unsigned long long bb = __ballot((kk >> j) & 1);
            same &= ((kk >> j) & 1) ? bb : ~bb;
        }
        rk[i] = (int)__popcll(same & lmask);
        if (cat[i] && rk[i] == 0)
            segCnt[kk][i * 4 + wvid] = (unsigned char)__popcll(same);
    }
    __syncthreads();

    // ---- Phase 2a: segPre (parallel) + wave-0 2-chunk prefix scan ----
    for (int j = tid; j < NB * 16; j += NT) {
        const int k = j >> 4, u = j & 15;
        int p = 0;
        for (int v = 0; v < u; ++v) p += (int)segCnt[k][v];
        segPre[k][u] = (unsigned short)p;
    }
    if (wvid == 0) {
        int tA = 0;
#pragma unroll
        for (int u = 0; u < 16; ++u) tA += (int)segCnt[lane][u];
        tA = (tA + 3) & ~3;
        int incA = tA;
#pragma unroll
        for (int d = 1; d < 64; d <<= 1) {
            const int o = __shfl_up(incA, d);
            if (lane >= d) incA += o;
        }
        const int carry = __shfl(incA, 63);
        segStart[lane] = incA - tA;
        int tB = 0;
        if (64 + lane < NB) {
#pragma unroll
            for (int u = 0; u < 16; ++u) tB += (int)segCnt[64 + lane][u];
            tB = (tB + 3) & ~3;
        }
        int incB = tB;
#pragma unroll
        for (int d = 1; d < 64; d <<= 1) {
            const int o = __shfl_up(incB, d);
            if (lane >= d) incB += o;
        }
        incB += carry;
        if (64 + lane < NB) segStart[64 + lane] = incB - tB;
        if (64 + lane == NB - 1) segStart[NB] = incB;
    }
    __syncthreads();

    // ---- Phase 2b: placement; slot in registers; cat in En mantissa LSBs ----
    int slot[4];
#pragma unroll
    for (int i = 0; i < 4; ++i) {
        slot[i] = 0;
        if (cat[i]) {
            const int k = key[i];
            slot[i] = segStart[k] + (int)segPre[k][i * 4 + wvid] + rk[i];
            const float cb = umin + ((float)k + 0.5f) * Wb;
            const float env = exp2f((uu[i] - cb) * L2E);
            unsigned eb = __float_as_uint(env);
            eb = (eb & ~3u) | (unsigned)cat[i];
            En[slot[i]] = __uint_as_float(eb);
        }
    }
    __syncthreads();     // segCnt/segPre dead -> Tab overlay valid

    const int nS = segStart[NB];
    const int nQ = nS >> 2;

    // ---- Phase 3a: Tab zeros + bucket-parallel BktQ + quad coefficients ----
    if (tid < 18 * 6) {                   // cols {0,1,128..131} per row
        const int row = tid / 6, ci = tid % 6;
        TabF[row * TCOLS + (ci < 2 ? ci : ci + 126)] = 0.f;  // disjoint from 2..127
    }
    if (tid < NB) {
        const int qa = segStart[tid] >> 2, qb = segStart[tid + 1] >> 2;
        for (int q = qa; q < qb; ++q) BktQ[q] = (unsigned char)tid;
    }
    for (int q = tid; q < nQ; q += NT) {
        const float4 e4v = *(const float4*)&En[4 * q];
        const float en[4] = {e4v.x, e4v.y, e4v.z, e4v.w};
        const int fl[4] = {(int)(__float_as_uint(e4v.x) & 3u),
                           (int)(__float_as_uint(e4v.y) & 3u),
                           (int)(__float_as_uint(e4v.z) & 3u),
                           (int)(__float_as_uint(e4v.w) & 3u)};
        const float s01 = en[0] + en[1], p01 = en[0] * en[1];
        const float s23 = en[2] + en[3], p23 = en[2] * en[3];
        const float e1 = s01 + s23;
        const float e2 = fmaf(s01, s23, p01 + p23);
        const float e3 = fmaf(s01, p23, s23 * p01);
        const float e4 = p01 * p23;
        float nA3 = 0.f, nA2 = 0.f, nA1 = 0.f, nA0 = 0.f;
        float nP3 = 0.f, nP2 = 0.f, nP1 = 0.f, nP0 = 0.f;
#pragma unroll
        for (int j = 0; j < 4; ++j) {
            const float b1 = e1 - en[j];
            const float b2 = fmaf(-en[j], b1, e2);
            const float b3 = fmaf(-en[j], b2, e3);
            const float nn = (float)(fl[j] >> 1) * en[j];
            const float pp = (float)(fl[j] & 1) * en[j];
            nA3 += nn; nA2 = fmaf(nn, b1, nA2); nA1 = fmaf(nn, b2, nA1); nA0 = fmaf(nn, b3, nA0);
            nP3 += pp; nP2 = fmaf(pp, b1, nP2); nP1 = fmaf(pp, b2, nP1); nP0 = fmaf(pp, b3, nP0);
        }
        CeAll[q] = make_float4(e1, e2, e3, e4);
        __half2 hA0 = __floats2half2_rn(nA3, nA2);
        __half2 hA1 = __floats2half2_rn(nA1, nA0);
        __half2 hP0 = __floats2half2_rn(nP3, nP2);
        __half2 hP1 = __floats2half2_rn(nP1, nP0);
        ChAll[q] = make_uint4(reinterpret_cast<unsigned&>(hA0), reinterpret_cast<unsigned&>(hA1),
                              reinterpret_cast<unsigned&>(hP0), reinterpret_cast<unsigned&>(hP1));
    }
    // ---- Phase 3b: per-bucket tail sums (4-term), 2 threads/bucket ----
    if (tid < NB * 2) {
        const int k = tid >> 1, o = tid & 1;
        float g1a=0,g2a=0,g3a=0,g4a=0,h1a=0,h2a=0,h3a=0,h4a=0,s0a=0;
        float g1p=0,g2p=0,g3p=0,g4p=0,h1p=0,h2p=0,h3p=0,h4p=0,s0p=0;
        for (int s = segStart[k] + o; s < segStart[k + 1]; s += 2) {
            const float en = En[s];
            const int f = (int)(__float_as_uint(en) & 3u);
            if (!f) continue;
            const float en2 = en * en, en3 = en2 * en, en4 = en2 * en2;
            const float ren = __builtin_amdgcn_rcpf(en);
            const float ren2 = ren * ren, ren3 = ren2 * ren, ren4 = ren2 * ren2;
            const float nf = (float)(f >> 1), pf = (float)(f & 1);
            g1a = fmaf(nf,en,g1a);  g2a = fmaf(nf,en2,g2a);  g3a = fmaf(nf,en3,g3a);  g4a = fmaf(nf,en4,g4a);
            h1a = fmaf(nf,ren,h1a); h2a = fmaf(nf,ren2,h2a); h3a = fmaf(nf,ren3,h3a); h4a = fmaf(nf,ren4,h4a); s0a += nf;
            g1p = fmaf(pf,en,g1p);  g2p = fmaf(pf,en2,g2p);  g3p = fmaf(pf,en3,g3p);  g4p = fmaf(pf,en4,g4p);
            h1p = fmaf(pf,ren,h1p); h2p = fmaf(pf,ren2,h2p); h3p = fmaf(pf,ren3,h3p); h4p = fmaf(pf,ren4,h4p); s0p += pf;
        }
#define RED2(v) v += __shfl_xor(v, 1)
        RED2(g1a); RED2(g2a); RED2(g3a); RED2(g4a); RED2(h1a); RED2(h2a); RED2(h3a); RED2(h4a); RED2(s0a);
        RED2(g1p); RED2(g2p); RED2(g3p); RED2(g4p); RED2(h1p); RED2(h2p); RED2(h3p); RED2(h4p); RED2(s0p);
#undef RED2
        if (o == 0) {
            TabF[(0*9+0)*TCOLS+k+2]=g1a; TabF[(0*9+1)*TCOLS+k+2]=g2a; TabF[(0*9+2)*TCOLS+k+2]=g3a; TabF[(0*9+3)*TCOLS+k+2]=g4a;
            TabF[(0*9+4)*TCOLS+k+2]=h1a; TabF[(0*9+5)*TCOLS+k+2]=h2a; TabF[(0*9+6)*TCOLS+k+2]=h3a; TabF[(0*9+7)*TCOLS+k+2]=h4a;
            TabF[(0*9+8)*TCOLS+k+2]=s0a;
            TabF[(1*9+0)*TCOLS+k+2]=g1p; TabF[(1*9+1)*TCOLS+k+2]=g2p; TabF[(1*9+2)*TCOLS+k+2]=g3p; TabF[(1*9+3)*TCOLS+k+2]=g4p;
            TabF[(1*9+4)*TCOLS+k+2]=h1p; TabF[(1*9+5)*TCOLS+k+2]=h2p; TabF[(1*9+6)*TCOLS+k+2]=h3p; TabF[(1*9+7)*TCOLS+k+2]=h4p;
            TabF[(1*9+8)*TCOLS+k+2]=s0p;
        }
    }
    __syncthreads();
    // ---- Phase 3c: 2-chunk wave scans, 18 rows over 4 waves ----
    for (int rowi = wvid; rowi < 18; rowi += 4) {
        const int r9 = rowi % 9;
        float* Trow = &TabF[rowi * TCOLS];
        const int deg = (r9 < 4) ? r9 + 1 : (r9 < 8 ? r9 - 3 : 0);
        const float lg = -Wb * L2E * (float)deg;   // log2(kp); deg 0 -> kp = 1
        const float kpv = exp2f(lg);
        if (r9 < 4) {            // prefix: y[k] = x[k] + kp*y[k-1]
            float vA = Trow[lane + 2];             // buckets 0..63
            float kpw = kpv;
#pragma unroll
            for (int d = 1; d < 64; d <<= 1) {
                const float o = __shfl_up(vA, d);
                if (lane >= d) vA = fmaf(kpw, o, vA);
                kpw *= kpw;
            }
            const float carry = __shfl(vA, 63);
            float vB = (64 + lane < NB) ? Trow[66 + lane] : 0.f;
            kpw = kpv;
#pragma unroll
            for (int d = 1; d < 64; d <<= 1) {
                const float o = __shfl_up(vB, d);
                if (lane >= d) vB = fmaf(kpw, o, vB);
                kpw *= kpw;
            }
            vB = fmaf(exp2f((float)(lane + 1) * lg), carry, vB);
            Trow[lane + 2] = vA;
            if (64 + lane < NB) Trow[66 + lane] = vB;
        } else {                 // suffix: y[k] = x[k] + kp*y[k+1]
            float vB = (64 + lane < NB) ? Trow[66 + lane] : 0.f;
            float kpw = kpv;
#pragma unroll
            for (int d = 1; d < 64; d <<= 1) {
                float o = __shfl_down(vB, d);
                if (lane + d > 63) o = 0.f;
                vB = fmaf(kpw, o, vB);
                kpw *= kpw;
            }
            const float carryB = __shfl(vB, 0);
            float vA = Trow[lane + 2];
            kpw = kpv;
#pragma unroll
            for (int d = 1; d < 64; d <<= 1) {
                float o = __shfl_down(vA, d);
                if (lane + d > 63) o = 0.f;
                vA = fmaf(kpw, o, vA);
                kpw *= kpw;
            }
            vA = fmaf(exp2f((float)(64 - lane) * lg), carryB, vA);
            Trow[lane + 2] = vA;
            if (64 + lane < NB) Trow[66 + lane] = vB;
        }
    }
    __syncthreads();

    // ---- Phase 4: band walk per quad (up to 2 quads/thread; nQ <= 328) ----
    float ANa[4] = {0,0,0,0}, APa[4] = {0,0,0,0};
    float ANb[4] = {0,0,0,0}, APb[4] = {0,0,0,0};

    auto process = [&](int q0, float* AN, float* AP) {
        const float4 x4 = *(const float4*)&En[4 * q0];
        const float xb[4] = {x4.x, x4.y, x4.z, x4.w};
        const int ib = BktQ[q0];
        const int klo = ib > 0 ? ib - 1 : 0;
        const int khi = ib < NB - 1 ? ib + 1 : NB - 1;
        const int qs  = segStart[klo] >> 2;
        const int qe  = segStart[khi + 1] >> 2;
        const int qo0 = segStart[ib] >> 2;
        const int qo1 = segStart[ib + 1] >> 2;

        auto quadrun = [&](int a0, int a1, const float* xs) {
            for (int q = a0; q < a1; ++q) {
                const float4 ce = CeAll[q];
                const uint4 ch = ChAll[q];
                const float2 a01 = __half22float2(*(const __half2*)&ch.x);
                const float2 a23 = __half22float2(*(const __half2*)&ch.y);
                const float2 p01 = __half22float2(*(const __half2*)&ch.z);
                const float2 p23 = __half22float2(*(const __half2*)&ch.w);
#pragma unroll
                for (int i = 0; i < 4; ++i) {
                    const float x = xs[i];
                    float t = x + ce.x; t = fmaf(t, x, ce.y); t = fmaf(t, x, ce.z);
                    const float D = fmaf(t, x, ce.w);
                    float u = fmaf(a01.x, x, a01.y); u = fmaf(u, x, a23.x);
                    const float NA = fmaf(u, x, a23.y);
                    float v = fmaf(p01.x, x, p01.y); v = fmaf(v, x, p23.x);
                    const float NP = fmaf(v, x, p23.y);
                    const float rd = __builtin_amdgcn_rcpf(D);
                    AN[i] = fmaf(NA, rd, AN[i]);
                    AP[i] = fmaf(NP, rd, AP[i]);
                }
            }
        };
        float xsl[4], xsh[4];
#pragma unroll
        for (int i = 0; i < 4; ++i) { xsl[i] = xb[i] * eWm; xsh[i] = xb[i] * kap1; }
        quadrun(qs,  qo0, xsl);
        quadrun(qo0, qo1, xb);
        quadrun(qo1, qe,  xsh);

        // 4-term out-of-band tails
        const float P1a = TabF[(0*9+0)*TCOLS+ib],   P2a = TabF[(0*9+1)*TCOLS+ib];
        const float P3a = TabF[(0*9+2)*TCOLS+ib],   P4a = TabF[(0*9+3)*TCOLS+ib];
        const float S1a = TabF[(0*9+4)*TCOLS+ib+4], S2a = TabF[(0*9+5)*TCOLS+ib+4];
        const float S3a = TabF[(0*9+6)*TCOLS+ib+4], S4a = TabF[(0*9+7)*TCOLS+ib+4];
        const float S0a = TabF[(0*9+8)*TCOLS+ib+4];
        const float P1p = TabF[(1*9+0)*TCOLS+ib],   P2p = TabF[(1*9+1)*TCOLS+ib];
        const float P3p = TabF[(1*9+2)*TCOLS+ib],   P4p = TabF[(1*9+3)*TCOLS+ib];
        const float S1p = TabF[(1*9+4)*TCOLS+ib+4], S2p = TabF[(1*9+5)*TCOLS+ib+4];
        const float S3p = TabF[(1*9+6)*TCOLS+ib+4], S4p = TabF[(1*9+7)*TCOLS+ib+4];
        const float S0p = TabF[(1*9+8)*TCOLS+ib+4];
#pragma unroll
        for (int i = 0; i < 4; ++i) {
            const float eb = xb[i];
            const float rb = __builtin_amdgcn_rcpf(eb);
            const float tq = rb * kap2, sq = eb * kap2;
            const float tq2 = tq * tq, tq3 = tq2 * tq, tq4 = tq2 * tq2;
            const float sq2 = sq * sq, sq3 = sq2 * sq, sq4 = sq2 * sq2;
            AN[i] += tq * P1a - tq2 * P2a + tq3 * P3a - tq4 * P4a
                   + S0a - sq * S1a + sq2 * S2a - sq3 * S3a + sq4 * S4a;
            AP[i] += tq * P1p - tq2 * P2p + tq3 * P3p - tq4 * P4p
                   + S0p - sq * S1p + sq2 * S2p - sq3 * S3p + sq4 * S4p;
        }
    };

    if (tid < nQ) process(tid, ANa, APa);
    if (tid + NT < nQ) process(tid + NT, ANb, APb);
    __syncthreads();   // all Cq reads done -> overlay RankA/RankP

    // ---- Phase 5: write ranks BY SLOT ----
    if (tid < nQ) {
#pragma unroll
        for (int i = 0; i < 4; ++i) { RankA[4 * tid + i] = ANa[i]; RankP[4 * tid + i] = APa[i]; }
    }
    if (tid + NT < nQ) {
#pragma unroll
        for (int i = 0; i < 4; ++i) { RankA[4 * (tid + NT) + i] = ANb[i]; RankP[4 * (tid + NT) + i] = APb[i]; }
    }
    __syncthreads();

    // ---- Phase 6: gather via register slot[], write rank_m ----
#pragma unroll
    for (int i = 0; i < 4; ++i) {
        const int c = tid + i * NT;
        const bool pf = (cat[i] & 1) != 0;
        const bool nf = (cat[i] & 2) != 0;
        const float rk_ = (pf ? 1.f + RankA[slot[i]] : 0.f) +
                          (nf ? 1.f + RankP[slot[i]] : 0.f);
        rank_ws[m * (B * B) + r * B + c] = rk_;
    }
}

__global__ __launch_bounds__(NT, 8)
void combine_kernel(const float* __restrict__ rank_ws,
                    const float* __restrict__ w_v, const float* __restrict__ w_l,
                    float* __restrict__ out) {
    const int i4 = (blockIdx.x * NT + threadIdx.x) * 4;
    const float4 rv = *(const float4*)&rank_ws[i4];
    const float4 rl = *(const float4*)&rank_ws[B * B + i4];
    const float4 wv = *(const float4*)&w_v[i4];
    const float4 wl = *(const float4*)&w_l[i4];
    float4 o;
    o.x = 61.f * (wv.x / (60.f + rv.x) + wl.x / (60.f + rl.x));
    o.y = 61.f * (wv.y / (60.f + rv.y) + wl.y / (60.f + rl.y));
    o.z = 61.f * (wv.z / (60.f + rv.z) + wl.z / (60.f + rl.z));
    o.w = 61.f * (wv.w / (60.f + rv.w) + wl.w / (60.f + rl.w));
    *(float4*)&out[i4] = o;
}

extern "C" void kernel_launch(void* const* d_in, const int* in_sizes, int n_in,
                              void* d_out, int out_size, void* d_ws, size_t ws_size,
                              hipStream_t stream) {
    const float* s_v = (const float*)d_in[0];
    const float* s_l = (const float*)d_in[1];
    const int* pos_mask = (const int*)d_in[2];
    const int* neg_mask = (const int*)d_in[3];
    const float* w_v = (const float*)d_in[4];
    const float* w_l = (const float*)d_in[5];
    float* out = (float*)d_out;
    float* rank_ws = (float*)d_ws;   // 2 * 1024 * 1024 floats = 8 MB

    rank_one_kernel<<<2 * B, NT, 0, stream>>>(s_v, s_l, pos_mask, neg_mask, rank_ws);
    combine_kernel<<<(B * B) / (NT * 4), NT, 0, stream>>>(rank_ws, w_v, w_l, out);
}

// Round 22
// 47.346 us; speedup vs baseline: 1.0606x; 1.0606x over previous
//
#include <hip/hip_runtime.h>
#include <hip/hip_fp16.h>

// DifferentiableRankIntegration, B=1024, tau=0.1, K=60.
// R22 = R20 (best: 48.7us, 8 blocks/CU) + two safe wins from R21:
//   (1) bucket-parallel BktQ fill (kills the per-quad 59-compare loop),
//   (2) second-quad guard for nQ>256 (free when inactive; removes a cliff).
// R21 lesson: band-narrowing past W=1.0 costs residency (8->6 blocks) and
// regresses -- the kernel is latency/phase-bound now, not in-band-bound.
// Algorithm: value-bucket compaction (NB=60, W>=1.0), en = e^{u-c_bkt} (cat
// in mantissa LSBs); in-band (ib-1..ib+1): exact weighted quartic rational
// (1 rcp / 4 a-terms, numerators via synthetic division, fp16-packed);
// out-of-band: 3-term sigma tails via geometric prefix/suffix tables;
// wave-parallel scans; bank-skewed coeffs; combine kernel fuses epilogue.

constexpr int B = 1024;
constexpr int NT = 256;
constexpr int NB = 60;
constexpr int SLOTCAP = 1216;      // 1024 + 3*NB pads, rounded to 16
constexpr int QCAP = SLOTCAP / 4;  // 304
constexpr int QPHYS = QCAP + (QCAP >> 4) + 1;  // 324 (skewed physical slots)
constexpr float L2E = 1.4426950408889634f;
constexpr int TCOLS = NB + 6;      // 66

constexpr int OFF_EN  = 0;                        // 4864 B
constexpr int OFF_CQ  = OFF_EN + SLOTCAP * 4;     // CeAll+ChAll = 2*324*16 = 10368 B
                                                  //  (phase>=5: RankA/P 9728 B)
constexpr int OFF_SEG = OFF_CQ + 2 * QPHYS * 16;  // segCnt 960 + segPre 1920
                                                  //  (phase>=3: Tab 14x66x4 = 3696)
constexpr int OFF_BKQ = OFF_SEG + 14 * TCOLS * 4; // BktQ 304 B
constexpr int OFF_SST = OFF_BKQ + QCAP;           // segStart 61*4 = 244 B
constexpr int OFF_RED = OFF_SST + (NB + 1) * 4;   // Red 32 B
constexpr int POOL_BYTES = ((OFF_RED + 32 + 15) / 16) * 16;  // 19520 B <= 20480

__global__ __launch_bounds__(NT, 8)
void rank_one_kernel(const float* __restrict__ s_v, const float* __restrict__ s_l,
                     const int* __restrict__ pos_m, const int* __restrict__ neg_m,
                     float* __restrict__ rank_ws) {
    __shared__ __align__(16) char pool[POOL_BYTES];
    float* En          = (float*)(pool + OFF_EN);
    float4* CeAll      = (float4*)(pool + OFF_CQ);            // e1..e4 (skewed)
    uint4* ChAll       = (uint4*)(pool + OFF_CQ + QPHYS*16);  // hA0,hA1,hP0,hP1
    unsigned char (*segCnt)[16]  = (unsigned char(*)[16])(pool + OFF_SEG);
    unsigned short (*segPre)[16] = (unsigned short(*)[16])(pool + OFF_SEG + NB*16);
    float* TabF        = (float*)(pool + OFF_SEG);   // overlay (post 2b)
    unsigned char* BktQ = (unsigned char*)(pool + OFF_BKQ);
    int* segStart      = (int*)(pool + OFF_SST);
    float* Red         = (float*)(pool + OFF_RED);
    float* RankA       = (float*)(pool + OFF_CQ);    // phase>=5 overlay
    float* RankP       = RankA + SLOTCAP;

    const int m = blockIdx.x >> 10;
    const int r = blockIdx.x & 1023;
    const float* __restrict__ S = m ? s_l : s_v;
    const int tid = threadIdx.x;
    const int lane = tid & 63;
    const int wvid = tid >> 6;
    const unsigned long long lmask = (1ull << lane) - 1ull;

    for (int s = tid; s < SLOTCAP; s += NT) En[s] = 0.f;  // pads: cat bits 0
    for (int j = tid; j < NB * 16 / 4; j += NT) ((int*)segCnt)[j] = 0;
    __syncthreads();

    // ---- Phase 1: read, u = s/tau, cat, row min/max ----
    float uu[4]; int cat[4];
    float mn = 1e30f, mx = -1e30f;
#pragma unroll
    for (int i = 0; i < 4; ++i) {
        const int c = tid + i * NT;
        uu[i] = S[r * B + c] * 10.0f;
        const int pf = pos_m[r * B + c] != 0, nf = neg_m[r * B + c] != 0;
        cat[i] = pf | (nf << 1);
        mn = fminf(mn, uu[i]); mx = fmaxf(mx, uu[i]);
    }
#pragma unroll
    for (int off = 1; off < 64; off <<= 1) {
        mn = fminf(mn, __shfl_xor(mn, off));
        mx = fmaxf(mx, __shfl_xor(mx, off));
    }
    if (lane == 0) { Red[wvid] = mn; Red[4 + wvid] = mx; }
    __syncthreads();

    const float lo = fminf(fminf(Red[0], Red[1]), fminf(Red[2], Red[3]));
    const float hi = fmaxf(fmaxf(Red[4], Red[5]), fmaxf(Red[6], Red[7]));
    const float umin = lo;
    const float Wb   = fmaxf((hi - lo) * (1.0001f / NB), 1.0f);
    const float invW = 1.0f / Wb;
    const float kap1 = exp2f(-Wb * L2E);
    const float kap2 = kap1 * kap1;
    const float kap3 = kap2 * kap1;
    const float eWm  = exp2f(Wb * L2E);

    // ---- Phase 1b: bucket keys; rank via 6 bit-ballots (NB<63, cat0 -> 63) ----
    int key[4], rk[4];
#pragma unroll
    for (int i = 0; i < 4; ++i) {
        int b = (int)((uu[i] - umin) * invW);
        b = b > NB - 1 ? NB - 1 : b;
        const int kk = cat[i] ? b : 63;
        key[i] = b;
        unsigned long long same = ~0ull;
#pragma unroll
        for (int j = 0; j < 6; ++j) {
            const unsigned long long bb = __ballot((kk >> j) & 1);
            same &= ((kk >> j) & 1) ? bb : ~bb;
        }
        rk[i] = (int)__popcll(same & lmask);
        if (cat[i] && rk[i] == 0)
            segCnt[kk][i * 4 + wvid] = (unsigned char)__popcll(same);
    }
    __syncthreads();

    // ---- Phase 2a: segPre (parallel) + wave-0 shfl prefix scan of lengths ----
    for (int j = tid; j < NB * 16; j += NT) {
        const int k = j >> 4, u = j & 15;
        int p = 0;
        for (int v = 0; v < u; ++v) p += (int)segCnt[k][v];
        segPre[k][u] = (unsigned short)p;
    }
    if (wvid == 0) {
        int t = 0;
        if (lane < NB) {
#pragma unroll
            for (int u = 0; u < 16; ++u) t += (int)segCnt[lane][u];
            t = (t + 3) & ~3;
        }
        int inc = t;
#pragma unroll
        for (int d = 1; d < 64; d <<= 1) {
            const int o = __shfl_up(inc, d);
            if (lane >= d) inc += o;
        }
        if (lane < NB) segStart[lane] = inc - t;
        if (lane == NB - 1) segStart[NB] = inc;
    }
    __syncthreads();

    // ---- Phase 2b: placement; slot in registers; cat in En mantissa LSBs ----
    int slot[4];
#pragma unroll
    for (int i = 0; i < 4; ++i) {
        slot[i] = 0;
        if (cat[i]) {
            const int k = key[i];
            slot[i] = segStart[k] + (int)segPre[k][i * 4 + wvid] + rk[i];
            const float cb = umin + ((float)k + 0.5f) * Wb;
            const float env = exp2f((uu[i] - cb) * L2E);
            unsigned eb = __float_as_uint(env);
            eb = (eb & ~3u) | (unsigned)cat[i];
            En[slot[i]] = __uint_as_float(eb);
        }
    }
    __syncthreads();     // segCnt/segPre dead -> Tab overlay valid

    const int nS = segStart[NB];
    const int nQ = nS >> 2;

    // ---- Phase 3a: Tab boundary zeros + bucket-parallel BktQ + coefficients ----
    if (tid < 14 * 6) {                   // cols {0,1,62,63,64,65} per row
        const int row = tid / 6, ci = tid % 6;
        TabF[row * TCOLS + (ci < 2 ? ci : ci + 60)] = 0.f;  // disjoint from 3b's 2..61
    }
    if (tid < NB) {                       // bucket-parallel BktQ fill (R21 win)
        const int qa = segStart[tid] >> 2, qb = segStart[tid + 1] >> 2;
        for (int q = qa; q < qb; ++q) BktQ[q] = (unsigned char)tid;
    }
    for (int q = tid; q < nQ; q += NT) {
        const float4 e4v = *(const float4*)&En[4 * q];
        const float en[4] = {e4v.x, e4v.y, e4v.z, e4v.w};
        const int fl[4] = {(int)(__float_as_uint(e4v.x) & 3u),
                           (int)(__float_as_uint(e4v.y) & 3u),
                           (int)(__float_as_uint(e4v.z) & 3u),
                           (int)(__float_as_uint(e4v.w) & 3u)};
        const float s01 = en[0] + en[1], p01 = en[0] * en[1];
        const float s23 = en[2] + en[3], p23 = en[2] * en[3];
        const float e1 = s01 + s23;
        const float e2 = fmaf(s01, s23, p01 + p23);
        const float e3 = fmaf(s01, p23, s23 * p01);
        const float e4 = p01 * p23;
        float nA3 = 0.f, nA2 = 0.f, nA1 = 0.f, nA0 = 0.f;
        float nP3 = 0.f, nP2 = 0.f, nP1 = 0.f, nP0 = 0.f;
#pragma unroll
        for (int j = 0; j < 4; ++j) {
            const float b1 = e1 - en[j];
            const float b2 = fmaf(-en[j], b1, e2);
            const float b3 = fmaf(-en[j], b2, e3);
            const float nn = (float)(fl[j] >> 1) * en[j];
            const float pp = (float)(fl[j] & 1) * en[j];
            nA3 += nn; nA2 = fmaf(nn, b1, nA2); nA1 = fmaf(nn, b2, nA1); nA0 = fmaf(nn, b3, nA0);
            nP3 += pp; nP2 = fmaf(pp, b1, nP2); nP1 = fmaf(pp, b2, nP1); nP0 = fmaf(pp, b3, nP0);
        }
        const int pq = q + (q >> 4);   // bank-skewed physical index
        CeAll[pq] = make_float4(e1, e2, e3, e4);
        __half2 hA0 = __floats2half2_rn(nA3, nA2);
        __half2 hA1 = __floats2half2_rn(nA1, nA0);
        __half2 hP0 = __floats2half2_rn(nP3, nP2);
        __half2 hP1 = __floats2half2_rn(nP1, nP0);
        ChAll[pq] = make_uint4(reinterpret_cast<unsigned&>(hA0), reinterpret_cast<unsigned&>(hA1),
                               reinterpret_cast<unsigned&>(hP0), reinterpret_cast<unsigned&>(hP1));
    }
    // ---- Phase 3b: per-bucket tail sums, 4 threads/bucket + shfl reduce ----
    if (tid < NB * 4) {
        const int k = tid >> 2, o = tid & 3;
        float g1a=0,g2a=0,g3a=0,h1a=0,h2a=0,h3a=0,s0a=0;
        float g1p=0,g2p=0,g3p=0,h1p=0,h2p=0,h3p=0,s0p=0;
        for (int s = segStart[k] + o; s < segStart[k + 1]; s += 4) {
            const float en = En[s];
            const int f = (int)(__float_as_uint(en) & 3u);
            if (!f) continue;
            const float en2 = en * en, en3 = en2 * en;
            const float ren = __builtin_amdgcn_rcpf(en);
            const float ren2 = ren * ren, ren3 = ren2 * ren;
            const float nf = (float)(f >> 1), pf = (float)(f & 1);
            g1a = fmaf(nf,en,g1a);  g2a = fmaf(nf,en2,g2a);  g3a = fmaf(nf,en3,g3a);
            h1a = fmaf(nf,ren,h1a); h2a = fmaf(nf,ren2,h2a); h3a = fmaf(nf,ren3,h3a); s0a += nf;
            g1p = fmaf(pf,en,g1p);  g2p = fmaf(pf,en2,g2p);  g3p = fmaf(pf,en3,g3p);
            h1p = fmaf(pf,ren,h1p); h2p = fmaf(pf,ren2,h2p); h3p = fmaf(pf,ren3,h3p); s0p += pf;
        }
#define RED4(v) v += __shfl_xor(v, 2); v += __shfl_xor(v, 1)
        RED4(g1a); RED4(g2a); RED4(g3a); RED4(h1a); RED4(h2a); RED4(h3a); RED4(s0a);
        RED4(g1p); RED4(g2p); RED4(g3p); RED4(h1p); RED4(h2p); RED4(h3p); RED4(s0p);
#undef RED4
        if (o == 0) {
            TabF[(0*7+0)*TCOLS+k+2]=g1a; TabF[(0*7+1)*TCOLS+k+2]=g2a; TabF[(0*7+2)*TCOLS+k+2]=g3a;
            TabF[(0*7+3)*TCOLS+k+2]=h1a; TabF[(0*7+4)*TCOLS+k+2]=h2a; TabF[(0*7+5)*TCOLS+k+2]=h3a;
            TabF[(0*7+6)*TCOLS+k+2]=s0a;
            TabF[(1*7+0)*TCOLS+k+2]=g1p; TabF[(1*7+1)*TCOLS+k+2]=g2p; TabF[(1*7+2)*TCOLS+k+2]=g3p;
            TabF[(1*7+3)*TCOLS+k+2]=h1p; TabF[(1*7+4)*TCOLS+k+2]=h2p; TabF[(1*7+5)*TCOLS+k+2]=h3p;
            TabF[(1*7+6)*TCOLS+k+2]=s0p;
        }
    }
    __syncthreads();
    // ---- Phase 3c: wave-parallel weighted scans (14 rows over 4 waves) ----
    for (int rowi = wvid; rowi < 14; rowi += 4) {
        const int r7 = rowi % 7;
        float* Trow = &TabF[rowi * TCOLS];
        float v = (lane < NB) ? Trow[lane + 2] : 0.f;
        if (r7 < 3) {          // prefix: y[k] = x[k] + kp*y[k-1]
            float kp = (r7 == 0) ? kap1 : (r7 == 1 ? kap2 : kap3);
#pragma unroll
            for (int d = 1; d < 64; d <<= 1) {
                const float o = __shfl_up(v, d);
                if (lane >= d) v = fmaf(kp, o, v);
                kp *= kp;
            }
        } else {               // suffix: y[k] = x[k] + kp*y[k+1]  (kp=1: plain sum)
            float kp = (r7 == 3) ? kap1 : (r7 == 4 ? kap2 : (r7 == 5 ? kap3 : 1.0f));
#pragma unroll
            for (int d = 1; d < 64; d <<= 1) {
                float o = __shfl_down(v, d);
                if (lane + d > 63) o = 0.f;
                v = fmaf(kp, o, v);
                kp *= kp;
            }
        }
        if (lane < NB) Trow[lane + 2] = v;
    }
    __syncthreads();

    // ---- Phase 4: band walk (contiguous ownership; 2nd-quad guard) ----
    float ANa[4] = {0,0,0,0}, APa[4] = {0,0,0,0};
    float ANb[4] = {0,0,0,0}, APb[4] = {0,0,0,0};

    auto process = [&](int q0, float* AN, float* AP) {
        const float4 x4 = *(const float4*)&En[4 * q0];
        const float xb[4] = {x4.x, x4.y, x4.z, x4.w};
        const int ib = BktQ[q0];
        const int klo = ib > 0 ? ib - 1 : 0;
        const int khi = ib < NB - 1 ? ib + 1 : NB - 1;
        const int qs  = segStart[klo] >> 2;
        const int qe  = segStart[khi + 1] >> 2;
        const int qo0 = segStart[ib] >> 2;
        const int qo1 = segStart[ib + 1] >> 2;

        auto quadrun = [&](int a0, int a1, const float* xs) {
            for (int q = a0; q < a1; ++q) {
                const int pq = q + (q >> 4);
                const float4 ce = CeAll[pq];
                const uint4 ch = ChAll[pq];
                const float2 a01 = __half22float2(*(const __half2*)&ch.x);
                const float2 a23 = __half22float2(*(const __half2*)&ch.y);
                const float2 p01 = __half22float2(*(const __half2*)&ch.z);
                const float2 p23 = __half22float2(*(const __half2*)&ch.w);
#pragma unroll
                for (int i = 0; i < 4; ++i) {
                    const float x = xs[i];
                    float t = x + ce.x; t = fmaf(t, x, ce.y); t = fmaf(t, x, ce.z);
                    const float D = fmaf(t, x, ce.w);
                    float u = fmaf(a01.x, x, a01.y); u = fmaf(u, x, a23.x);
                    const float NA = fmaf(u, x, a23.y);
                    float v = fmaf(p01.x, x, p01.y); v = fmaf(v, x, p23.x);
                    const float NP = fmaf(v, x, p23.y);
                    const float rd = __builtin_amdgcn_rcpf(D);
                    AN[i] = fmaf(NA, rd, AN[i]);
                    AP[i] = fmaf(NP, rd, AP[i]);
                }
            }
        };
        float xsl[4], xsh[4];
#pragma unroll
        for (int i = 0; i < 4; ++i) { xsl[i] = xb[i] * eWm; xsh[i] = xb[i] * kap1; }
        quadrun(qs,  qo0, xsl);   // below-band buckets: fc = e^W
        quadrun(qo0, qo1, xb);    // own bucket: fc = 1
        quadrun(qo1, qe,  xsh);   // above-band buckets: fc = kappa

        // 3-term out-of-band tails
        const float P1a = TabF[(0*7+0)*TCOLS+ib],   P2a = TabF[(0*7+1)*TCOLS+ib],   P3a = TabF[(0*7+2)*TCOLS+ib];
        const float S1a = TabF[(0*7+3)*TCOLS+ib+4], S2a = TabF[(0*7+4)*TCOLS+ib+4], S3a = TabF[(0*7+5)*TCOLS+ib+4];
        const float S0a = TabF[(0*7+6)*TCOLS+ib+4];
        const float P1p = TabF[(1*7+0)*TCOLS+ib],   P2p = TabF[(1*7+1)*TCOLS+ib],   P3p = TabF[(1*7+2)*TCOLS+ib];
        const float S1p = TabF[(1*7+3)*TCOLS+ib+4], S2p = TabF[(1*7+4)*TCOLS+ib+4], S3p = TabF[(1*7+5)*TCOLS+ib+4];
        const float S0p = TabF[(1*7+6)*TCOLS+ib+4];
#pragma unroll
        for (int i = 0; i < 4; ++i) {
            const float eb = xb[i];
            const float rb = __builtin_amdgcn_rcpf(eb);
            const float tq = rb * kap2, sq = eb * kap2;
            const float tq2 = tq * tq, tq3 = tq2 * tq;
            const float sq2 = sq * sq, sq3 = sq2 * sq;
            AN[i] += tq * P1a - tq2 * P2a + tq3 * P3a
                   + S0a - sq * S1a + sq2 * S2a - sq3 * S3a;
            AP[i] += tq * P1p - tq2 * P2p + tq3 * P3p
                   + S0p - sq * S1p + sq2 * S2p - sq3 * S3p;
        }
    };

    if (tid < nQ) process(tid, ANa, APa);
    if (tid + NT < nQ) process(tid + NT, ANb, APb);
    __syncthreads();   // all Cq reads done -> overlay RankA/RankP

    // ---- Phase 5: write ranks BY SLOT ----
    if (tid < nQ) {
#pragma unroll
        for (int i = 0; i < 4; ++i) { RankA[4 * tid + i] = ANa[i]; RankP[4 * tid + i] = APa[i]; }
    }
    if (tid + NT < nQ) {
#pragma unroll
        for (int i = 0; i < 4; ++i) { RankA[4 * (tid + NT) + i] = ANb[i]; RankP[4 * (tid + NT) + i] = APb[i]; }
    }
    __syncthreads();

    // ---- Phase 6: gather via register slot[], write rank_m ----
#pragma unroll
    for (int i = 0; i < 4; ++i) {
        const int c = tid + i * NT;
        const bool pf = (cat[i] & 1) != 0;
        const bool nf = (cat[i] & 2) != 0;
        const float rk_ = (pf ? 1.f + RankA[slot[i]] : 0.f) +
                          (nf ? 1.f + RankP[slot[i]] : 0.f);
        rank_ws[m * (B * B) + r * B + c] = rk_;
    }
}

__global__ __launch_bounds__(NT, 8)
void combine_kernel(const float* __restrict__ rank_ws,
                    const float* __restrict__ w_v, const float* __restrict__ w_l,
                    float* __restrict__ out) {
    const int i4 = (blockIdx.x * NT + threadIdx.x) * 4;
    const float4 rv = *(const float4*)&rank_ws[i4];
    const float4 rl = *(const float4*)&rank_ws[B * B + i4];
    const float4 wv = *(const float4*)&w_v[i4];
    const float4 wl = *(const float4*)&w_l[i4];
    float4 o;
    o.x = 61.f * (wv.x / (60.f + rv.x) + wl.x / (60.f + rl.x));
    o.y = 61.f * (wv.y / (60.f + rv.y) + wl.y / (60.f + rl.y));
    o.z = 61.f * (wv.z / (60.f + rv.z) + wl.z / (60.f + rl.z));
    o.w = 61.f * (wv.w / (60.f + rv.w) + wl.w / (60.f + rl.w));
    *(float4*)&out[i4] = o;
}

extern "C" void kernel_launch(void* const* d_in, const int* in_sizes, int n_in,
                              void* d_out, int out_size, void* d_ws, size_t ws_size,
                              hipStream_t stream) {
    const float* s_v = (const float*)d_in[0];
    const float* s_l = (const float*)d_in[1];
    const int* pos_mask = (const int*)d_in[2];
    const int* neg_mask = (const int*)d_in[3];
    const float* w_v = (const float*)d_in[4];
    const float* w_l = (const float*)d_in[5];
    float* out = (float*)d_out;
    float* rank_ws = (float*)d_ws;   // 2 * 1024 * 1024 floats = 8 MB

    rank_one_kernel<<<2 * B, NT, 0, stream>>>(s_v, s_l, pos_mask, neg_mask, rank_ws);
    combine_kernel<<<(B * B) / (NT * 4), NT, 0, stream>>>(rank_ws, w_v, w_l, out);
}

// Round 23
// 31.210 us; speedup vs baseline: 1.6089x; 1.5170x over previous
//
#include <hip/hip_runtime.h>
#include <hip/hip_fp16.h>

// DifferentiableRankIntegration, B=1024, tau=0.1, K=60.
// R23 = R22's verified compaction/quartic/tail machinery, but AN(u),AP(u)
// are evaluated ONLY at the NB=60 bucket-center nodes (per node: in-band
// quartic walk with constant x in {e^W,1,kappa}, tails with eb=1 -> uniform
// kappa^2 factors), then per-item values come from 4-point Lagrange cubic
// interpolation on the uniform node grid. AN = sum of logistics is smooth
// (|AN''''| <~ 20/u^4), so interp error <= W^4*0.023*|AN''''| ~ 0.5 rank
// units -- far inside the ~2.4-rank output budget. Phase-4 work drops ~30x.
constexpr int B = 1024;
constexpr int NT = 256;
constexpr int NB = 60;
constexpr int SLOTCAP = 1216;      // 1024 + 3*NB pads, rounded to 16
constexpr int QCAP = SLOTCAP / 4;  // 304
constexpr int QPHYS = QCAP + (QCAP >> 4) + 1;  // 324 (skewed physical slots)
constexpr float L2E = 1.4426950408889634f;
constexpr int TCOLS = NB + 6;      // 66

constexpr int OFF_EN  = 0;                        // 4864 B
constexpr int OFF_CQ  = OFF_EN + SLOTCAP * 4;     // CeAll+ChAll = 2*324*16 = 10368 B
                                                  //  (post-4: ANnode/APnode overlay)
constexpr int OFF_SEG = OFF_CQ + 2 * QPHYS * 16;  // segCnt 960 + segPre 1920
                                                  //  (phase>=3: Tab 14x66x4 = 3696)
constexpr int OFF_BKQ = OFF_SEG + 14 * TCOLS * 4; // (unused spare, 304 B)
constexpr int OFF_SST = OFF_BKQ + QCAP;           // segStart 61*4 = 244 B
constexpr int OFF_RED = OFF_SST + (NB + 1) * 4;   // Red 32 B
constexpr int POOL_BYTES = ((OFF_RED + 32 + 15) / 16) * 16;  // 19520 B <= 20480

__global__ __launch_bounds__(NT, 8)
void rank_one_kernel(const float* __restrict__ s_v, const float* __restrict__ s_l,
                     const int* __restrict__ pos_m, const int* __restrict__ neg_m,
                     float* __restrict__ rank_ws) {
    __shared__ __align__(16) char pool[POOL_BYTES];
    float* En          = (float*)(pool + OFF_EN);
    float4* CeAll      = (float4*)(pool + OFF_CQ);            // e1..e4 (skewed)
    uint4* ChAll       = (uint4*)(pool + OFF_CQ + QPHYS*16);  // hA0,hA1,hP0,hP1
    unsigned char (*segCnt)[16]  = (unsigned char(*)[16])(pool + OFF_SEG);
    unsigned short (*segPre)[16] = (unsigned short(*)[16])(pool + OFF_SEG + NB*16);
    float* TabF        = (float*)(pool + OFF_SEG);   // overlay (post 2b)
    int* segStart      = (int*)(pool + OFF_SST);
    float* Red         = (float*)(pool + OFF_RED);
    float* ANnode      = (float*)(pool + OFF_CQ);    // post-phase-4 overlay
    float* APnode      = ANnode + 64;

    const int m = blockIdx.x >> 10;
    const int r = blockIdx.x & 1023;
    const float* __restrict__ S = m ? s_l : s_v;
    const int tid = threadIdx.x;
    const int lane = tid & 63;
    const int wvid = tid >> 6;
    const unsigned long long lmask = (1ull << lane) - 1ull;

    for (int s = tid; s < SLOTCAP; s += NT) En[s] = 0.f;  // pads: cat bits 0
    for (int j = tid; j < NB * 16 / 4; j += NT) ((int*)segCnt)[j] = 0;
    __syncthreads();

    // ---- Phase 1: read, u = s/tau, cat, row min/max ----
    float uu[4]; int cat[4];
    float mn = 1e30f, mx = -1e30f;
#pragma unroll
    for (int i = 0; i < 4; ++i) {
        const int c = tid + i * NT;
        uu[i] = S[r * B + c] * 10.0f;
        const int pf = pos_m[r * B + c] != 0, nf = neg_m[r * B + c] != 0;
        cat[i] = pf | (nf << 1);
        mn = fminf(mn, uu[i]); mx = fmaxf(mx, uu[i]);
    }
#pragma unroll
    for (int off = 1; off < 64; off <<= 1) {
        mn = fminf(mn, __shfl_xor(mn, off));
        mx = fmaxf(mx, __shfl_xor(mx, off));
    }
    if (lane == 0) { Red[wvid] = mn; Red[4 + wvid] = mx; }
    __syncthreads();

    const float lo = fminf(fminf(Red[0], Red[1]), fminf(Red[2], Red[3]));
    const float hi = fmaxf(fmaxf(Red[4], Red[5]), fmaxf(Red[6], Red[7]));
    const float umin = lo;
    const float Wb   = fmaxf((hi - lo) * (1.0001f / NB), 1.0f);
    const float invW = 1.0f / Wb;
    const float kap1 = exp2f(-Wb * L2E);
    const float kap2 = kap1 * kap1;
    const float kap3 = kap2 * kap1;
    const float eWm  = exp2f(Wb * L2E);

    // ---- Phase 1b: bucket keys; rank via 6 bit-ballots (NB<63, cat0 -> 63) ----
    int key[4], rk[4];
#pragma unroll
    for (int i = 0; i < 4; ++i) {
        int b = (int)((uu[i] - umin) * invW);
        b = b > NB - 1 ? NB - 1 : b;
        const int kk = cat[i] ? b : 63;
        key[i] = b;
        unsigned long long same = ~0ull;
#pragma unroll
        for (int j = 0; j < 6; ++j) {
            const unsigned long long bb = __ballot((kk >> j) & 1);
            same &= ((kk >> j) & 1) ? bb : ~bb;
        }
        rk[i] = (int)__popcll(same & lmask);
        if (cat[i] && rk[i] == 0)
            segCnt[kk][i * 4 + wvid] = (unsigned char)__popcll(same);
    }
    __syncthreads();

    // ---- Phase 2a: segPre (parallel) + wave-0 shfl prefix scan of lengths ----
    for (int j = tid; j < NB * 16; j += NT) {
        const int k = j >> 4, u = j & 15;
        int p = 0;
        for (int v = 0; v < u; ++v) p += (int)segCnt[k][v];
        segPre[k][u] = (unsigned short)p;
    }
    if (wvid == 0) {
        int t = 0;
        if (lane < NB) {
#pragma unroll
            for (int u = 0; u < 16; ++u) t += (int)segCnt[lane][u];
            t = (t + 3) & ~3;
        }
        int inc = t;
#pragma unroll
        for (int d = 1; d < 64; d <<= 1) {
            const int o = __shfl_up(inc, d);
            if (lane >= d) inc += o;
        }
        if (lane < NB) segStart[lane] = inc - t;
        if (lane == NB - 1) segStart[NB] = inc;
    }
    __syncthreads();

    // ---- Phase 2b: placement (scatter En); cat in En mantissa LSBs ----
#pragma unroll
    for (int i = 0; i < 4; ++i) {
        if (cat[i]) {
            const int k = key[i];
            const int slot = segStart[k] + (int)segPre[k][i * 4 + wvid] + rk[i];
            const float cb = umin + ((float)k + 0.5f) * Wb;
            const float env = exp2f((uu[i] - cb) * L2E);
            unsigned eb = __float_as_uint(env);
            eb = (eb & ~3u) | (unsigned)cat[i];
            En[slot] = __uint_as_float(eb);
        }
    }
    __syncthreads();     // segCnt/segPre dead -> Tab overlay valid

    const int nS = segStart[NB];
    const int nQ = nS >> 2;

    // ---- Phase 3a: Tab boundary zeros + quad coefficients ----
    if (tid < 14 * 6) {                   // cols {0,1,62,63,64,65} per row
        const int row = tid / 6, ci = tid % 6;
        TabF[row * TCOLS + (ci < 2 ? ci : ci + 60)] = 0.f;  // disjoint from 3b's 2..61
    }
    for (int q = tid; q < nQ; q += NT) {
        const float4 e4v = *(const float4*)&En[4 * q];
        const float en[4] = {e4v.x, e4v.y, e4v.z, e4v.w};
        const int fl[4] = {(int)(__float_as_uint(e4v.x) & 3u),
                           (int)(__float_as_uint(e4v.y) & 3u),
                           (int)(__float_as_uint(e4v.z) & 3u),
                           (int)(__float_as_uint(e4v.w) & 3u)};
        const float s01 = en[0] + en[1], p01 = en[0] * en[1];
        const float s23 = en[2] + en[3], p23 = en[2] * en[3];
        const float e1 = s01 + s23;
        const float e2 = fmaf(s01, s23, p01 + p23);
        const float e3 = fmaf(s01, p23, s23 * p01);
        const float e4 = p01 * p23;
        float nA3 = 0.f, nA2 = 0.f, nA1 = 0.f, nA0 = 0.f;
        float nP3 = 0.f, nP2 = 0.f, nP1 = 0.f, nP0 = 0.f;
#pragma unroll
        for (int j = 0; j < 4; ++j) {
            const float b1 = e1 - en[j];
            const float b2 = fmaf(-en[j], b1, e2);
            const float b3 = fmaf(-en[j], b2, e3);
            const float nn = (float)(fl[j] >> 1) * en[j];
            const float pp = (float)(fl[j] & 1) * en[j];
            nA3 += nn; nA2 = fmaf(nn, b1, nA2); nA1 = fmaf(nn, b2, nA1); nA0 = fmaf(nn, b3, nA0);
            nP3 += pp; nP2 = fmaf(pp, b1, nP2); nP1 = fmaf(pp, b2, nP1); nP0 = fmaf(pp, b3, nP0);
        }
        const int pq = q + (q >> 4);   // bank-skewed physical index
        CeAll[pq] = make_float4(e1, e2, e3, e4);
        __half2 hA0 = __floats2half2_rn(nA3, nA2);
        __half2 hA1 = __floats2half2_rn(nA1, nA0);
        __half2 hP0 = __floats2half2_rn(nP3, nP2);
        __half2 hP1 = __floats2half2_rn(nP1, nP0);
        ChAll[pq] = make_uint4(reinterpret_cast<unsigned&>(hA0), reinterpret_cast<unsigned&>(hA1),
                               reinterpret_cast<unsigned&>(hP0), reinterpret_cast<unsigned&>(hP1));
    }
    // ---- Phase 3b: per-bucket tail sums, 4 threads/bucket + shfl reduce ----
    if (tid < NB * 4) {
        const int k = tid >> 2, o = tid & 3;
        float g1a=0,g2a=0,g3a=0,h1a=0,h2a=0,h3a=0,s0a=0;
        float g1p=0,g2p=0,g3p=0,h1p=0,h2p=0,h3p=0,s0p=0;
        for (int s = segStart[k] + o; s < segStart[k + 1]; s += 4) {
            const float en = En[s];
            const int f = (int)(__float_as_uint(en) & 3u);
            if (!f) continue;
            const float en2 = en * en, en3 = en2 * en;
            const float ren = __builtin_amdgcn_rcpf(en);
            const float ren2 = ren * ren, ren3 = ren2 * ren;
            const float nf = (float)(f >> 1), pf = (float)(f & 1);
            g1a = fmaf(nf,en,g1a);  g2a = fmaf(nf,en2,g2a);  g3a = fmaf(nf,en3,g3a);
            h1a = fmaf(nf,ren,h1a); h2a = fmaf(nf,ren2,h2a); h3a = fmaf(nf,ren3,h3a); s0a += nf;
            g1p = fmaf(pf,en,g1p);  g2p = fmaf(pf,en2,g2p);  g3p = fmaf(pf,en3,g3p);
            h1p = fmaf(pf,ren,h1p); h2p = fmaf(pf,ren2,h2p); h3p = fmaf(pf,ren3,h3p); s0p += pf;
        }
#define RED4(v) v += __shfl_xor(v, 2); v += __shfl_xor(v, 1)
        RED4(g1a); RED4(g2a); RED4(g3a); RED4(h1a); RED4(h2a); RED4(h3a); RED4(s0a);
        RED4(g1p); RED4(g2p); RED4(g3p); RED4(h1p); RED4(h2p); RED4(h3p); RED4(s0p);
#undef RED4
        if (o == 0) {
            TabF[(0*7+0)*TCOLS+k+2]=g1a; TabF[(0*7+1)*TCOLS+k+2]=g2a; TabF[(0*7+2)*TCOLS+k+2]=g3a;
            TabF[(0*7+3)*TCOLS+k+2]=h1a; TabF[(0*7+4)*TCOLS+k+2]=h2a; TabF[(0*7+5)*TCOLS+k+2]=h3a;
            TabF[(0*7+6)*TCOLS+k+2]=s0a;
            TabF[(1*7+0)*TCOLS+k+2]=g1p; TabF[(1*7+1)*TCOLS+k+2]=g2p; TabF[(1*7+2)*TCOLS+k+2]=g3p;
            TabF[(1*7+3)*TCOLS+k+2]=h1p; TabF[(1*7+4)*TCOLS+k+2]=h2p; TabF[(1*7+5)*TCOLS+k+2]=h3p;
            TabF[(1*7+6)*TCOLS+k+2]=s0p;
        }
    }
    __syncthreads();
    // ---- Phase 3c: wave-parallel weighted scans (14 rows over 4 waves) ----
    for (int rowi = wvid; rowi < 14; rowi += 4) {
        const int r7 = rowi % 7;
        float* Trow = &TabF[rowi * TCOLS];
        float v = (lane < NB) ? Trow[lane + 2] : 0.f;
        if (r7 < 3) {          // prefix: y[k] = x[k] + kp*y[k-1]
            float kp = (r7 == 0) ? kap1 : (r7 == 1 ? kap2 : kap3);
#pragma unroll
            for (int d = 1; d < 64; d <<= 1) {
                const float o = __shfl_up(v, d);
                if (lane >= d) v = fmaf(kp, o, v);
                kp *= kp;
            }
        } else {               // suffix: y[k] = x[k] + kp*y[k+1]  (kp=1: plain sum)
            float kp = (r7 == 3) ? kap1 : (r7 == 4 ? kap2 : (r7 == 5 ? kap3 : 1.0f));
#pragma unroll
            for (int d = 1; d < 64; d <<= 1) {
                float o = __shfl_down(v, d);
                if (lane + d > 63) o = 0.f;
                v = fmaf(kp, o, v);
                kp *= kp;
            }
        }
        if (lane < NB) Trow[lane + 2] = v;
    }
    __syncthreads();

    // ---- Phase 4: node evaluation (4 threads per node) ----
    const int nd = tid >> 2;           // node = bucket center index
    const int no = tid & 3;
    float ANv = 0.f, APv = 0.f;
    if (nd < NB) {
        const int klo = nd > 0 ? nd - 1 : 0;
        const int khi = nd < NB - 1 ? nd + 1 : NB - 1;
        const int qs  = segStart[klo] >> 2;
        const int qe  = segStart[khi + 1] >> 2;
        const int qo0 = segStart[nd] >> 2;
        const int qo1 = segStart[nd + 1] >> 2;
        for (int q = qs + no; q < qe; q += 4) {
            const float x = (q < qo0) ? eWm : ((q >= qo1) ? kap1 : 1.0f);
            const int pq = q + (q >> 4);
            const float4 ce = CeAll[pq];
            const uint4 ch = ChAll[pq];
            const float2 a01 = __half22float2(*(const __half2*)&ch.x);
            const float2 a23 = __half22float2(*(const __half2*)&ch.y);
            const float2 p01 = __half22float2(*(const __half2*)&ch.z);
            const float2 p23 = __half22float2(*(const __half2*)&ch.w);
            float t = x + ce.x; t = fmaf(t, x, ce.y); t = fmaf(t, x, ce.z);
            const float D = fmaf(t, x, ce.w);
            float u = fmaf(a01.x, x, a01.y); u = fmaf(u, x, a23.x);
            const float NA = fmaf(u, x, a23.y);
            float v = fmaf(p01.x, x, p01.y); v = fmaf(v, x, p23.x);
            const float NP = fmaf(v, x, p23.y);
            const float rd = __builtin_amdgcn_rcpf(D);
            ANv = fmaf(NA, rd, ANv);
            APv = fmaf(NP, rd, APv);
        }
        ANv += __shfl_xor(ANv, 2); ANv += __shfl_xor(ANv, 1);
        APv += __shfl_xor(APv, 2); APv += __shfl_xor(APv, 1);
        // tails at node (eb = 1 -> all factors are kappa2 powers)
        const float k2 = kap2, k4 = kap2 * kap2, k6 = k4 * kap2;
        ANv += k2 * TabF[(0*7+0)*TCOLS+nd] - k4 * TabF[(0*7+1)*TCOLS+nd] + k6 * TabF[(0*7+2)*TCOLS+nd]
             + TabF[(0*7+6)*TCOLS+nd+4] - k2 * TabF[(0*7+3)*TCOLS+nd+4]
             + k4 * TabF[(0*7+4)*TCOLS+nd+4] - k6 * TabF[(0*7+5)*TCOLS+nd+4];
        APv += k2 * TabF[(1*7+0)*TCOLS+nd] - k4 * TabF[(1*7+1)*TCOLS+nd] + k6 * TabF[(1*7+2)*TCOLS+nd]
             + TabF[(1*7+6)*TCOLS+nd+4] - k2 * TabF[(1*7+3)*TCOLS+nd+4]
             + k4 * TabF[(1*7+4)*TCOLS+nd+4] - k6 * TabF[(1*7+5)*TCOLS+nd+4];
    }
    __syncthreads();   // Cq reads done -> node arrays may overlay
    if (nd < NB && no == 0) { ANnode[nd] = ANv; APnode[nd] = APv; }
    __syncthreads();

    // ---- Phase 5: per-item 4-point Lagrange interpolation + write ----
#pragma unroll
    for (int i = 0; i < 4; ++i) {
        const float t = (uu[i] - umin) * invW - 0.5f;   // node j sits at t = j
        int jc = (int)floorf(t);
        jc = jc < 1 ? 1 : (jc > NB - 3 ? NB - 3 : jc);
        const float s = t - (float)jc;
        const float sm = s - 1.f, sp = s + 1.f, s2 = s - 2.f;
        const float wL = -s * sm * s2 * (1.f / 6.f);
        const float w0 = sp * sm * s2 * 0.5f;
        const float w1 = -sp * s * s2 * 0.5f;
        const float w2 = sp * s * sm * (1.f / 6.f);
        const float AN = wL * ANnode[jc-1] + w0 * ANnode[jc] + w1 * ANnode[jc+1] + w2 * ANnode[jc+2];
        const float AP = wL * APnode[jc-1] + w0 * APnode[jc] + w1 * APnode[jc+1] + w2 * APnode[jc+2];
        const bool pf = (cat[i] & 1) != 0;
        const bool nf = (cat[i] & 2) != 0;
        const float rk_ = (pf ? 1.f + AN : 0.f) + (nf ? 1.f + AP : 0.f);
        rank_ws[m * (B * B) + r * B + (tid + i * NT)] = rk_;
    }
}

__global__ __launch_bounds__(NT, 8)
void combine_kernel(const float* __restrict__ rank_ws,
                    const float* __restrict__ w_v, const float* __restrict__ w_l,
                    float* __restrict__ out) {
    const int i4 = (blockIdx.x * NT + threadIdx.x) * 4;
    const float4 rv = *(const float4*)&rank_ws[i4];
    const float4 rl = *(const float4*)&rank_ws[B * B + i4];
    const float4 wv = *(const float4*)&w_v[i4];
    const float4 wl = *(const float4*)&w_l[i4];
    float4 o;
    o.x = 61.f * (wv.x / (60.f + rv.x) + wl.x / (60.f + rl.x));
    o.y = 61.f * (wv.y / (60.f + rv.y) + wl.y / (60.f + rl.y));
    o.z = 61.f * (wv.z / (60.f + rv.z) + wl.z / (60.f + rl.z));
    o.w = 61.f * (wv.w / (60.f + rv.w) + wl.w / (60.f + rl.w));
    *(float4*)&out[i4] = o;
}

extern "C" void kernel_launch(void* const* d_in, const int* in_sizes, int n_in,
                              void* d_out, int out_size, void* d_ws, size_t ws_size,
                              hipStream_t stream) {
    const float* s_v = (const float*)d_in[0];
    const float* s_l = (const float*)d_in[1];
    const int* pos_mask = (const int*)d_in[2];
    const int* neg_mask = (const int*)d_in[3];
    const float* w_v = (const float*)d_in[4];
    const float* w_l = (const float*)d_in[5];
    float* out = (float*)d_out;
    float* rank_ws = (float*)d_ws;   // 2 * 1024 * 1024 floats = 8 MB

    rank_one_kernel<<<2 * B, NT, 0, stream>>>(s_v, s_l, pos_mask, neg_mask, rank_ws);
    combine_kernel<<<(B * B) / (NT * 4), NT, 0, stream>>>(rank_ws, w_v, w_l, out);
}